// Round 6
// baseline (149.593 us; speedup 1.0000x reference)
//
#include <hip/hip_runtime.h>

#define Bv 4
#define Vv 50000
#define Cv 160

typedef float v2f __attribute__((ext_vector_type(2)));

// Kernel 1: per-(b,c) affine table A[b][c][12]:
//   A[0..8]  = R row-major (rows b1,b2,b3)
//   A[9..11] = center + V_nodes - R*center
// so out[b,v,:] = M·x_v + t with [M|t] = sum_c W[v,c]*A[b,c,:]
__global__ void precompute_A(const float* __restrict__ X,
                             const float* __restrict__ Vn,
                             const float* __restrict__ r6,
                             const int* __restrict__ idx,
                             float* __restrict__ A) {
    int i = blockIdx.x * blockDim.x + threadIdx.x;
    if (i >= Bv * Cv) return;
    int b = i / Cv, c = i % Cv;

    const float* d6 = r6 + (size_t)(b * Cv + c) * 6;
    float a1x = d6[0], a1y = d6[1], a1z = d6[2];
    float a2x = d6[3], a2y = d6[4], a2z = d6[5];

    float n1 = fmaxf(sqrtf(a1x*a1x + a1y*a1y + a1z*a1z), 1e-8f);
    float b1x = a1x / n1, b1y = a1y / n1, b1z = a1z / n1;

    float d = b1x*a2x + b1y*a2y + b1z*a2z;
    float px = a2x - d*b1x, py = a2y - d*b1y, pz = a2z - d*b1z;
    float n2 = fmaxf(sqrtf(px*px + py*py + pz*pz), 1e-8f);
    float b2x = px / n2, b2y = py / n2, b2z = pz / n2;

    float b3x = b1y*b2z - b1z*b2y;
    float b3y = b1z*b2x - b1x*b2z;
    float b3z = b1x*b2y - b1y*b2x;

    int iv = idx[c];
    const float* xc = X + ((size_t)b * Vv + iv) * 3;
    float cx = xc[0], cy = xc[1], cz = xc[2];
    const float* vn = Vn + (size_t)(b * Cv + c) * 3;
    float vx = vn[0], vy = vn[1], vz = vn[2];

    float* Ao = A + (size_t)(b * Cv + c) * 12;
    Ao[0] = b1x; Ao[1] = b1y; Ao[2] = b1z;
    Ao[3] = b2x; Ao[4] = b2y; Ao[5] = b2z;
    Ao[6] = b3x; Ao[7] = b3y; Ao[8] = b3z;
    Ao[9]  = cx + vx - (b1x*cx + b1y*cy + b1z*cz);
    Ao[10] = cy + vy - (b2x*cx + b2y*cy + b2z*cz);
    Ao[11] = cz + vz - (b3x*cx + b3y*cy + b3z*cz);
}

// Kernel 2: R4 shape (782 blocks x 256 thr = 4 waves/block, 1 vertex/lane,
// wave w -> batch b=w, all loads on the vector/vmcnt path; A hits L1 via
// same-address broadcast). NEW vs R4: accumulators are 6 x v2f over PAIRS
// of j-components -> v_pk_fma_f32 halves FMA issue count at unchanged
// parallelism (the R5 mistake was halving wave count instead).
__global__ __launch_bounds__(256) void deform_main(const float* __restrict__ X,
                                                   const float* __restrict__ W,
                                                   const float* __restrict__ A,
                                                   float* __restrict__ out) {
    const int tid  = threadIdx.x;
    const int lane = tid & 63;
    const int b    = tid >> 6;            // uniform in fact; stays on vector path
    const int v0   = blockIdx.x * 64;
    const int v    = v0 + lane;
    const bool valid = (v < Vv);
    const int vc   = valid ? v : (Vv - 1);

    const float4* __restrict__ Wrow = (const float4*)(W + (size_t)vc * Cv);  // 40 x float4
    const float4* __restrict__ A4   = (const float4*)(A + (size_t)b * Cv * 12);

    const float* xp = X + ((size_t)b * Vv + vc) * 3;
    float x0 = xp[0], x1 = xp[1], x2 = xp[2];

    // acc[0]=(M00,M01) acc[1]=(M02,M10) acc[2]=(M11,M12)
    // acc[3]=(M20,M21) acc[4]=(M22,T0)  acc[5]=(T1,T2)
    v2f acc[6];
#pragma unroll
    for (int j = 0; j < 6; ++j) acc[j] = (v2f){0.0f, 0.0f};

#pragma unroll 2
    for (int c4 = 0; c4 < Cv / 4; ++c4) {
        float4 wq = Wrow[c4];
        const float wj[4] = {wq.x, wq.y, wq.z, wq.w};
#pragma unroll
        for (int j = 0; j < 4; ++j) {
            int c = c4 * 4 + j;
            float4 a0 = A4[c * 3 + 0];   // M00 M01 M02 M10
            float4 a1 = A4[c * 3 + 1];   // M11 M12 M20 M21
            float4 a2 = A4[c * 3 + 2];   // M22 T0  T1  T2
            v2f w = (v2f){wj[j], wj[j]};
            acc[0] = __builtin_elementwise_fma(w, (v2f){a0.x, a0.y}, acc[0]);
            acc[1] = __builtin_elementwise_fma(w, (v2f){a0.z, a0.w}, acc[1]);
            acc[2] = __builtin_elementwise_fma(w, (v2f){a1.x, a1.y}, acc[2]);
            acc[3] = __builtin_elementwise_fma(w, (v2f){a1.z, a1.w}, acc[3]);
            acc[4] = __builtin_elementwise_fma(w, (v2f){a2.x, a2.y}, acc[4]);
            acc[5] = __builtin_elementwise_fma(w, (v2f){a2.z, a2.w}, acc[5]);
        }
    }

    if (valid) {
        float o0 = acc[0].x*x0 + acc[0].y*x1 + acc[1].x*x2 + acc[4].y;
        float o1 = acc[1].y*x0 + acc[2].x*x1 + acc[2].y*x2 + acc[5].x;
        float o2 = acc[3].x*x0 + acc[3].y*x1 + acc[4].x*x2 + acc[5].y;
        float* op = out + ((size_t)b * Vv + v) * 3;
        op[0] = o0; op[1] = o1; op[2] = o2;
    }
}

extern "C" void kernel_launch(void* const* d_in, const int* in_sizes, int n_in,
                              void* d_out, int out_size, void* d_ws, size_t ws_size,
                              hipStream_t stream) {
    const float* X   = (const float*)d_in[0];  // (B,V,3) fp32
    const float* Vn  = (const float*)d_in[1];  // (B,C,3) fp32
    const float* r6  = (const float*)d_in[2];  // (B,C,6) fp32
    const float* W   = (const float*)d_in[3];  // (V,C)   fp32
    const int*   idx = (const int*)d_in[4];    // (C,)    int32
    float* out = (float*)d_out;                // (B,V,3) fp32
    float* A = (float*)d_ws;                   // B*C*12 floats = 30720 B

    precompute_A<<<(Bv * Cv + 255) / 256, 256, 0, stream>>>(X, Vn, r6, idx, A);
    deform_main<<<(Vv + 63) / 64, 256, 0, stream>>>(X, W, A, out);
}

// Round 7
// 100.133 us; speedup vs baseline: 1.4939x; 1.4939x over previous
//
#include <hip/hip_runtime.h>

#define Bv 4
#define Vv 50000
#define Cv 160

// Kernel 1: per-(b,c) affine table A[b][c][12]:
//   A[0..8]  = R row-major (rows b1,b2,b3)
//   A[9..11] = center + V_nodes - R*center
// so out[b,v,:] = M·x_v + t with [M|t] = sum_c W[v,c]*A[b,c,:]
__global__ void precompute_A(const float* __restrict__ X,
                             const float* __restrict__ Vn,
                             const float* __restrict__ r6,
                             const int* __restrict__ idx,
                             float* __restrict__ A) {
    int i = blockIdx.x * blockDim.x + threadIdx.x;
    if (i >= Bv * Cv) return;
    int b = i / Cv, c = i % Cv;

    const float* d6 = r6 + (size_t)(b * Cv + c) * 6;
    float a1x = d6[0], a1y = d6[1], a1z = d6[2];
    float a2x = d6[3], a2y = d6[4], a2z = d6[5];

    float n1 = fmaxf(sqrtf(a1x*a1x + a1y*a1y + a1z*a1z), 1e-8f);
    float b1x = a1x / n1, b1y = a1y / n1, b1z = a1z / n1;

    float d = b1x*a2x + b1y*a2y + b1z*a2z;
    float px = a2x - d*b1x, py = a2y - d*b1y, pz = a2z - d*b1z;
    float n2 = fmaxf(sqrtf(px*px + py*py + pz*pz), 1e-8f);
    float b2x = px / n2, b2y = py / n2, b2z = pz / n2;

    float b3x = b1y*b2z - b1z*b2y;
    float b3y = b1z*b2x - b1x*b2z;
    float b3z = b1x*b2y - b1y*b2x;

    int iv = idx[c];
    const float* xc = X + ((size_t)b * Vv + iv) * 3;
    float cx = xc[0], cy = xc[1], cz = xc[2];
    const float* vn = Vn + (size_t)(b * Cv + c) * 3;
    float vx = vn[0], vy = vn[1], vz = vn[2];

    float* Ao = A + (size_t)(b * Cv + c) * 12;
    Ao[0] = b1x; Ao[1] = b1y; Ao[2] = b1z;
    Ao[3] = b2x; Ao[4] = b2y; Ao[5] = b2z;
    Ao[6] = b3x; Ao[7] = b3y; Ao[8] = b3z;
    Ao[9]  = cx + vx - (b1x*cx + b1y*cy + b1z*cz);
    Ao[10] = cy + vy - (b2x*cx + b2y*cy + b2z*cz);
    Ao[11] = cz + vz - (b3x*cx + b3y*cy + b3z*cz);
}

// Kernel 2: 512 threads = 8 waves per block, 64 vertices/block.
//   wave w: batch b = w&3, K-half h = w>>2 (c in [80h, 80h+80)).
// Hot loop: W via per-lane global float4 (vmcnt path), A via wave-uniform
// scalar loads (s_load, lgkmcnt, scalar pipe — zero VALU/VMEM issue cost,
// sL1-cached). The two counters are INDEPENDENT — unlike R2/R3 where LDS
// reads shared lgkmcnt with the s_loads and serialized. No LDS in the loop;
// LDS used once in the epilogue to combine the two K-halves.
__global__ __launch_bounds__(512) void deform_main(const float* __restrict__ X,
                                                   const float* __restrict__ W,
                                                   const float* __restrict__ A,
                                                   float* __restrict__ out) {
    __shared__ float P[4 * 64 * 13];  // upper-half partials, pad 13 vs bank stride

    const int tid  = threadIdx.x;
    const int lane = tid & 63;
    const int wv   = __builtin_amdgcn_readfirstlane(tid >> 6);  // 0..7 uniform
    const int b    = wv & 3;
    const int half = wv >> 2;
    const int v0   = blockIdx.x * 64;
    const int v    = v0 + lane;
    const bool valid = (v < Vv);
    const int vc   = valid ? v : (Vv - 1);

    // W: 20 float4 per K-half, per-lane row (vector path)
    const float4* __restrict__ Wrow =
        (const float4*)(W + (size_t)vc * Cv) + half * 20;
    // A: wave-uniform base -> compiler scalarizes to s_load
    const float* __restrict__ Ab = A + ((size_t)b * Cv + (size_t)half * 80) * 12;

    float acc[12];
#pragma unroll
    for (int j = 0; j < 12; ++j) acc[j] = 0.0f;

#pragma unroll 2
    for (int c4 = 0; c4 < 20; ++c4) {
        float4 wq = Wrow[c4];
        const float wj[4] = {wq.x, wq.y, wq.z, wq.w};
#pragma unroll
        for (int j = 0; j < 4; ++j) {
            const float* a = Ab + (size_t)(c4 * 4 + j) * 12;  // uniform -> s_load
            float w = wj[j];
#pragma unroll
            for (int k = 0; k < 12; ++k) acc[k] = fmaf(w, a[k], acc[k]);
        }
    }

    // Combine K-halves: upper waves dump partials to LDS.
    if (half) {
        float* p = &P[(b * 64 + lane) * 13];
#pragma unroll
        for (int j = 0; j < 12; ++j) p[j] = acc[j];
    }
    __syncthreads();

    if (!half) {
        const float* p = &P[(b * 64 + lane) * 13];
#pragma unroll
        for (int j = 0; j < 12; ++j) acc[j] += p[j];

        if (valid) {
            const float* xp = X + ((size_t)b * Vv + v) * 3;
            float x0 = xp[0], x1 = xp[1], x2 = xp[2];
            // acc[0..8] = M row-major, acc[9..11] = T
            float o0 = acc[0]*x0 + acc[1]*x1 + acc[2]*x2 + acc[9];
            float o1 = acc[3]*x0 + acc[4]*x1 + acc[5]*x2 + acc[10];
            float o2 = acc[6]*x0 + acc[7]*x1 + acc[8]*x2 + acc[11];
            float* op = out + ((size_t)b * Vv + v) * 3;
            op[0] = o0; op[1] = o1; op[2] = o2;
        }
    }
}

extern "C" void kernel_launch(void* const* d_in, const int* in_sizes, int n_in,
                              void* d_out, int out_size, void* d_ws, size_t ws_size,
                              hipStream_t stream) {
    const float* X   = (const float*)d_in[0];  // (B,V,3) fp32
    const float* Vn  = (const float*)d_in[1];  // (B,C,3) fp32
    const float* r6  = (const float*)d_in[2];  // (B,C,6) fp32
    const float* W   = (const float*)d_in[3];  // (V,C)   fp32
    const int*   idx = (const int*)d_in[4];    // (C,)    int32
    float* out = (float*)d_out;                // (B,V,3) fp32
    float* A = (float*)d_ws;                   // B*C*12 floats = 30720 B

    precompute_A<<<(Bv * Cv + 255) / 256, 256, 0, stream>>>(X, Vn, r6, idx, A);
    deform_main<<<(Vv + 63) / 64, 512, 0, stream>>>(X, W, A, out);
}